// Round 5
// baseline (160.593 us; speedup 1.0000x reference)
//
#include <hip/hip_runtime.h>
#include <math.h>

// Problem constants (fixed by the reference).
#define BB 8
#define LL 12
#define TT 36
#define DD 1024
#define FF 3
#define CC 32
#define NDC 16              // d-chunks in k_mq (64 d each)

// ---------------------------------------------------------------------------
// K1: partial scores. grid (96,16) = 1536 blocks (6/CU, 24 waves/CU).
// 256 threads = (c=32) x (s=8, 8 d each). q[8] in registers from x_local.
// Per t: 6 float4 xh loads (broadcast over c-lanes) + 32 FMA; in-wave
// __shfl_down(32) folds the two s per wave -> part[36][4][32] (18 KB LDS),
// block epilogue folds 4 waves -> mqp[bl][t][dc][c].
// ---------------------------------------------------------------------------
__global__ __launch_bounds__(256) void k_mq(const float* __restrict__ xl,
                                            const float* __restrict__ xh,
                                            const float* __restrict__ Wm,
                                            const float* __restrict__ bm,
                                            const float* __restrict__ Wq,
                                            const float* __restrict__ bq,
                                            float* __restrict__ mqp) {
  __shared__ float part[TT][4][CC];     // 18 KB
  const int bl = blockIdx.x;            // 0..95
  const int dc = blockIdx.y;            // 0..15 (64-d chunk)
  const int tid = threadIdx.x;
  const int c  = tid & 31;
  const int s  = tid >> 5;              // 0..7 (8-d sub)
  const int wv = tid >> 6;              // 0..3
  const int lane = tid & 63;
  const int d0 = dc * 64 + s * 8;

  // q[c, d0..d0+7] in registers.
  const float wq0 = Wq[c * 3 + 0], wq1 = Wq[c * 3 + 1], wq2 = Wq[c * 3 + 2];
  const float bq0 = bq[c];
  float q[8];
  {
    const float4* xlr = (const float4*)(xl + ((size_t)bl * DD + d0) * 3);
    float4 xb[6];
    #pragma unroll
    for (int i = 0; i < 6; ++i) xb[i] = xlr[i];
    const float* x = (const float*)xb;
    #pragma unroll
    for (int k = 0; k < 8; ++k)
      q[k] = fmaf(wq0, x[k * 3 + 0], fmaf(wq1, x[k * 3 + 1], fmaf(wq2, x[k * 3 + 2], bq0)));
  }

  const float w0 = Wm[c * 3 + 0], w1 = Wm[c * 3 + 1], w2 = Wm[c * 3 + 2];
  const float b0 = bm[c];

  #pragma unroll 2
  for (int t = 0; t < TT; ++t) {
    const float4* xr = (const float4*)(xh + (((size_t)bl * TT + t) * DD + d0) * 3);
    float4 xb[6];
    #pragma unroll
    for (int i = 0; i < 6; ++i) xb[i] = xr[i];
    const float* x = (const float*)xb;
    float a0 = 0.f, a1 = 0.f;
    #pragma unroll
    for (int k = 0; k < 8; k += 2) {
      a0 = fmaf(fmaf(w0, x[(k+0)*3], fmaf(w1, x[(k+0)*3+1], fmaf(w2, x[(k+0)*3+2], b0))), q[k+0], a0);
      a1 = fmaf(fmaf(w0, x[(k+1)*3], fmaf(w1, x[(k+1)*3+1], fmaf(w2, x[(k+1)*3+2], b0))), q[k+1], a1);
    }
    float a = a0 + a1;
    a += __shfl_down(a, 32);            // fold the two s-halves of the wave
    if (lane < 32) part[t][wv][c] = a;
  }
  __syncthreads();

  // 1152 outputs across 256 threads: fold 4 wave-partials, store with dc.
  for (int idx = tid; idx < TT * CC; idx += 256) {
    const int t  = idx >> 5;
    const int cc = idx & 31;
    const float v = (part[t][0][cc] + part[t][1][cc]) +
                    (part[t][2][cc] + part[t][3][cc]);
    mqp[(((size_t)bl * TT + t) * NDC + dc) * CC + cc] = v;
  }
}

// ---------------------------------------------------------------------------
// K2: reduce mqp over dc, relu+softmax over t, write att[bl][t][c].
// grid (96); 256 threads. Done ONCE per bl (k_out previously redid this
// 16x per bl with 32 active threads and a 288-deep load chain).
// ---------------------------------------------------------------------------
__global__ __launch_bounds__(256) void k_soft(const float* __restrict__ mqp,
                                              float* __restrict__ att_g) {
  __shared__ float S[TT][CC];
  __shared__ float mxv[CC], inv[CC];
  const int bl = blockIdx.x;
  const int tid = threadIdx.x;

  for (int idx = tid; idx < TT * CC; idx += 256) {
    const int t = idx >> 5;
    const int c = idx & 31;
    const float* p = mqp + (((size_t)bl * TT + t) * NDC) * CC + c;
    float v = 0.f;
    #pragma unroll
    for (int j = 0; j < NDC; ++j) v += p[j * CC];
    S[t][c] = fmaxf(v, 0.f);            // relu
  }
  __syncthreads();

  if (tid < CC) {
    const int c = tid;
    float mx = 0.f;                     // relu >= 0 -> valid seed
    #pragma unroll
    for (int t = 0; t < TT; ++t) mx = fmaxf(mx, S[t][c]);
    float ssum = 0.f;
    #pragma unroll
    for (int t = 0; t < TT; ++t) ssum += __expf(S[t][c] - mx);
    mxv[c] = mx;
    inv[c] = 1.f / ssum;
  }
  __syncthreads();

  for (int idx = tid; idx < TT * CC; idx += 256) {
    const int t = idx >> 5;
    const int c = idx & 31;
    att_g[((size_t)bl * TT + t) * CC + c] = __expf(S[t][c] - mxv[c]) * inv[c];
  }
}

// ---------------------------------------------------------------------------
// K3: memory read + residual. grid (96,4,4) = 1536 blocks (24 waves/CU).
// 256 threads = 256 d-lanes; 8 channels/thread (blockIdx.z). Prologue:
// coalesced float4 copy of att[36][32] into LDS (all 256 threads, ~2 instrs).
// Main: zero cross-thread reduction; att via float4 LDS broadcast.
// ---------------------------------------------------------------------------
__global__ __launch_bounds__(256) void k_out(const float* __restrict__ xl,
                                             const float* __restrict__ xh,
                                             const float* __restrict__ att_g,
                                             const float* __restrict__ Wq,
                                             const float* __restrict__ bq,
                                             const float* __restrict__ Wc,
                                             const float* __restrict__ bc,
                                             float* __restrict__ out) {
  __shared__ __align__(16) float att[TT][CC];
  const int bl = blockIdx.x;            // 0..95
  const int b = bl / LL, l = bl % LL;
  const int dc = blockIdx.y;            // 0..3 (256-d chunk)
  const int cg = blockIdx.z;            // 0..3 (8-channel group)
  const int tid = threadIdx.x;

  {
    const float4* src = (const float4*)(att_g + (size_t)bl * TT * CC);
    float4* dst = (float4*)att;
    for (int idx = tid; idx < TT * CC / 4; idx += 256) dst[idx] = src[idx];
  }
  __syncthreads();

  const int d = dc * 256 + tid;
  const int c0 = cg * 8;

  float w[8][3], bb[8];
  #pragma unroll
  for (int u = 0; u < 8; ++u) {
    w[u][0] = Wc[(c0 + u) * 3 + 0];
    w[u][1] = Wc[(c0 + u) * 3 + 1];
    w[u][2] = Wc[(c0 + u) * 3 + 2];
    bb[u]   = bc[c0 + u];
  }

  float acc[8];
  #pragma unroll
  for (int u = 0; u < 8; ++u) acc[u] = 0.f;

  #pragma unroll 4
  for (int t = 0; t < TT; ++t) {
    const float* p = xh + (((size_t)bl * TT + t) * DD + d) * 3;
    const float x0 = p[0], x1 = p[1], x2 = p[2];
    const float4 a0 = *(const float4*)&att[t][c0 + 0];  // LDS broadcast
    const float4 a1 = *(const float4*)&att[t][c0 + 4];
    acc[0] = fmaf(a0.x, fmaf(w[0][0], x0, fmaf(w[0][1], x1, fmaf(w[0][2], x2, bb[0]))), acc[0]);
    acc[1] = fmaf(a0.y, fmaf(w[1][0], x0, fmaf(w[1][1], x1, fmaf(w[1][2], x2, bb[1]))), acc[1]);
    acc[2] = fmaf(a0.z, fmaf(w[2][0], x0, fmaf(w[2][1], x1, fmaf(w[2][2], x2, bb[2]))), acc[2]);
    acc[3] = fmaf(a0.w, fmaf(w[3][0], x0, fmaf(w[3][1], x1, fmaf(w[3][2], x2, bb[3]))), acc[3]);
    acc[4] = fmaf(a1.x, fmaf(w[4][0], x0, fmaf(w[4][1], x1, fmaf(w[4][2], x2, bb[4]))), acc[4]);
    acc[5] = fmaf(a1.y, fmaf(w[5][0], x0, fmaf(w[5][1], x1, fmaf(w[5][2], x2, bb[5]))), acc[5]);
    acc[6] = fmaf(a1.z, fmaf(w[6][0], x0, fmaf(w[6][1], x1, fmaf(w[6][2], x2, bb[6]))), acc[6]);
    acc[7] = fmaf(a1.w, fmaf(w[7][0], x0, fmaf(w[7][1], x1, fmaf(w[7][2], x2, bb[7]))), acc[7]);
  }

  const float y0 = xl[((size_t)bl * DD + d) * 3 + 0];
  const float y1 = xl[((size_t)bl * DD + d) * 3 + 1];
  const float y2 = xl[((size_t)bl * DD + d) * 3 + 2];
  #pragma unroll
  for (int u = 0; u < 8; ++u) {
    const int c = c0 + u;
    const float qv = fmaf(Wq[c * 3 + 0], y0,
                     fmaf(Wq[c * 3 + 1], y1,
                     fmaf(Wq[c * 3 + 2], y2, bq[c])));
    out[(((size_t)b * CC + c) * LL + l) * DD + d] = qv + acc[u];
  }
}

// ---------------------------------------------------------------------------
extern "C" void kernel_launch(void* const* d_in, const int* in_sizes, int n_in,
                              void* d_out, int out_size, void* d_ws, size_t ws_size,
                              hipStream_t stream) {
  const float* xl = (const float*)d_in[0];  // (B,L,D,F)
  const float* xh = (const float*)d_in[1];  // (B,L,T,D,F)
  const float* Wq = (const float*)d_in[2];
  const float* bq = (const float*)d_in[3];
  const float* Wm = (const float*)d_in[4];
  const float* bm = (const float*)d_in[5];
  const float* Wc = (const float*)d_in[6];
  const float* bc = (const float*)d_in[7];
  float* out = (float*)d_out;               // (B,C,L,D)

  float* mqp   = (float*)d_ws;                               // [bl][t][16][c], 7.1 MB
  float* att_g = mqp + (size_t)BB * LL * TT * NDC * CC;      // [bl][t][c], 0.44 MB

  k_mq  <<<dim3(BB * LL, NDC), 256, 0, stream>>>(xl, xh, Wm, bm, Wq, bq, mqp);
  k_soft<<<dim3(BB * LL),      256, 0, stream>>>(mqp, att_g);
  k_out <<<dim3(BB * LL, 4, 4), 256, 0, stream>>>(xl, xh, att_g, Wq, bq, Wc, bc, out);
}